// Round 12
// baseline (193.599 us; speedup 1.0000x reference)
//
#include <hip/hip_runtime.h>
#include <stdint.h>

// Problem constants
#define B_    8
#define CIN   512
#define NPIX  16384
#define CK    256
#define KCTX  64
#define CV    256

typedef _Float16 f16;
typedef _Float16 f16x4 __attribute__((ext_vector_type(4)));
typedef _Float16 f16x8 __attribute__((ext_vector_type(8)));
typedef float    f32x4 __attribute__((ext_vector_type(4)));

#define LOG2E 1.44269504f

// ws layout (bytes). Tables in exact MFMA fragment order (rounds 6-11, verified).
// WQK: A-frag for sim.  byte = ((((s*4+mi)*2+kk)*4+g)*16+ln)*16 + 2*j
//      holds Wqk^T(c,m)*1/16 with c = 64s+32kk+8g+j, m = 16mi+ln
// WPV: B-frag for out.  byte = (((ct*2+kk)*4+g)*16+lnc)*16 + 2*j
//      holds Wpv(c,m) with c = 16ct+lnc, m = 16*(2kk+(j>>2))+4g+(j&3)
// ATTN: A-frag for out. byte = n*128 + kk*64 + 16*g + 2*j
//      holds attn(n,m) f16 with m = 32kk + 16*(j>>2) + 4g + (j&3)
#define WQK_OFF  0           // 512 KB : [b][64 KB]
#define WPV_OFF  524288      // 512 KB : [b][64 KB]
#define ATTN_OFF 1048576     // 16.8 MB: [b][n][128 B]

__device__ __forceinline__ void gl_lds16(const void* g, void* l) {
    __builtin_amdgcn_global_load_lds(
        (const __attribute__((address_space(1))) uint32_t*)g,
        (__attribute__((address_space(3))) uint32_t*)l, 16, 0, 0);
}

// ---------------------------------------------------------------------------
// prep: grid (4, B), 1024 threads, 64 KB LDS.  (unchanged from rounds 6-11)
// ---------------------------------------------------------------------------
__global__ __launch_bounds__(1024) void prep(const float* __restrict__ ctx,
                                             const float* __restrict__ Wk,
                                             const float* __restrict__ Wv,
                                             const float* __restrict__ Wq,
                                             const float* __restrict__ Wp,
                                             char* __restrict__ ws) {
    __shared__ char lds[65536];
    char* ctx_t = lds;              // 32 KB
    char* kv_s  = lds + 32768;      // 32 KB

    const int p = blockIdx.x;
    const int b = blockIdx.y;
    const int path = p >> 1, h = p & 1;
    const int t = threadIdx.x;
    const int w = t >> 6, l = t & 63, g = l >> 4, ln = l & 15;

    // ---- stage ctx transposed: ctx_t[m][c] f16 swz ----
    {
        const int m4 = (t & 15) * 4, c4 = (t >> 4) * 4;
        const float* cp = ctx + (size_t)b * (CV * KCTX) + (size_t)c4 * KCTX + m4;
        f32x4 xr[4];
        #pragma unroll
        for (int i = 0; i < 4; ++i) xr[i] = *(const f32x4*)(cp + (size_t)i * KCTX);
        #pragma unroll
        for (int j = 0; j < 4; ++j) {
            f16x4 v4; v4[0] = (f16)xr[0][j]; v4[1] = (f16)xr[1][j]; v4[2] = (f16)xr[2][j]; v4[3] = (f16)xr[3][j];
            int m = m4 + j;
            *(f16x4*)(ctx_t + m * 512 + 16 * (((c4 >> 3) & 31) ^ (m & 7)) + 2 * (c4 & 7)) = v4;
        }
    }
    __syncthreads();

    // ---- kv GEMM: D[row][m] = (path? Wv : Wk) * ctx, K=256 ----
    {
        const float* W = path ? Wv : Wk;
        const int rbase = 64 * (w >> 2);
        const int mm = 16 * (w & 3) + ln;
        f32x4 acc[4] = {};
        for (int ks = 0; ks < 8; ++ks) {
            f16x8 bf = *(const f16x8*)(ctx_t + mm * 512 + 16 * ((4 * ks + g) ^ (mm & 7)));
            #pragma unroll
            for (int mi = 0; mi < 4; ++mi) {
                int row = rbase + 16 * mi + ln;
                const float* wp0 = W + (size_t)row * CV + 32 * ks + 8 * g;
                f32x4 lo = *(const f32x4*)wp0, hi = *(const f32x4*)(wp0 + 4);
                f16x8 af;
                #pragma unroll
                for (int j = 0; j < 4; ++j) { af[j] = (f16)lo[j]; af[4 + j] = (f16)hi[j]; }
                acc[mi] = __builtin_amdgcn_mfma_f32_16x16x32_f16(af, bf, acc[mi], 0, 0, 0);
            }
        }
        #pragma unroll
        for (int mi = 0; mi < 4; ++mi)
            #pragma unroll
            for (int r = 0; r < 4; ++r) {
                int row = rbase + 16 * mi + 4 * g + r;
                *(f16*)(kv_s + mm * 512 + 16 * ((((row >> 3) & 31)) ^ (mm & 7)) + 2 * (row & 7)) = (f16)acc[mi][r];
            }
    }
    __syncthreads();

    if (path == 0) {
        // ---- Wqk^T[c][m] = sum_kk Wq[kk][c] k[kk][m]; A gathered from global ----
        f32x4 acc2[4] = {};
        const int cA = 256 * h + 16 * w + ln;
        const float* qcol = Wq + cA;
        for (int ks = 0; ks < 8; ++ks) {
            f16x8 af;
            #pragma unroll
            for (int j = 0; j < 8; ++j)
                af[j] = (f16)qcol[(size_t)(32 * ks + 8 * g + j) * CIN];
            #pragma unroll
            for (int ni = 0; ni < 4; ++ni) {
                int m2 = 16 * ni + ln;
                f16x8 bf = *(const f16x8*)(kv_s + m2 * 512 + 16 * ((4 * ks + g) ^ (m2 & 7)));
                acc2[ni] = __builtin_amdgcn_mfma_f32_16x16x32_f16(af, bf, acc2[ni], 0, 0, 0);
            }
        }
        char* dst = ws + WQK_OFF + b * 65536;
        #pragma unroll
        for (int ni = 0; ni < 4; ++ni)
            #pragma unroll
            for (int r = 0; r < 4; ++r) {
                int c = 256 * h + 16 * w + 4 * g + r;     // k-dim index of sim GEMM
                int s  = c >> 6, kk = (c >> 5) & 1, gk = (c >> 3) & 3, j = c & 7;
                int byte = ((((s * 4 + ni) * 2 + kk) * 4 + gk) * 16 + ln) * 16 + 2 * j;
                *(f16*)(dst + byte) = (f16)(acc2[ni][r] * 0.0625f);   // fold scale 1/16
            }
    } else {
        // ---- Wpv[c][m] = sum_v Wp[c][v] v[v][m]; A direct from global ----
        f32x4 acc2[4] = {};
        const int cA = 256 * h + 16 * w + ln;
        for (int ks = 0; ks < 8; ++ks) {
            const float* pp = Wp + (size_t)cA * CV + 32 * ks + 8 * g;
            f32x4 lo = *(const f32x4*)pp, hi = *(const f32x4*)(pp + 4);
            f16x8 af;
            #pragma unroll
            for (int j = 0; j < 4; ++j) { af[j] = (f16)lo[j]; af[4 + j] = (f16)hi[j]; }
            #pragma unroll
            for (int ni = 0; ni < 4; ++ni) {
                int m2 = 16 * ni + ln;
                f16x8 bf = *(const f16x8*)(kv_s + m2 * 512 + 16 * ((4 * ks + g) ^ (m2 & 7)));
                acc2[ni] = __builtin_amdgcn_mfma_f32_16x16x32_f16(af, bf, acc2[ni], 0, 0, 0);
            }
        }
        char* dst = ws + WPV_OFF + b * 65536;
        #pragma unroll
        for (int ni = 0; ni < 4; ++ni) {
            const int kkm = ni >> 1;
            const int gm  = ln >> 2;
            const int jm  = 4 * (ni & 1) + (ln & 3);
            #pragma unroll
            for (int r = 0; r < 4; ++r) {
                int c = 256 * h + 16 * w + 4 * g + r;     // output-channel index
                int ct = c >> 4, lnc = c & 15;
                int byte = (((ct * 2 + kkm) * 4 + gm) * 16 + lnc) * 16 + 2 * jm;
                *(f16*)(dst + byte) = (f16)acc2[ni][r];
            }
        }
    }
}

// ---------------------------------------------------------------------------
// simk: read-bound half. 256 threads = 4 independent waves, each owns 32 px
// and a private 8 KB double-buffered LDS slice (round-8 structure, verbatim).
// Output: attn in A-FRAGMENT ORDER, 4 x 16 B stores per lane.
// ---------------------------------------------------------------------------
__global__ __launch_bounds__(256, 4) void simk(const float* __restrict__ x,
                                               const char* __restrict__ ws,
                                               char* __restrict__ attn) {
    __shared__ char lds[32768];
    const int b = blockIdx.y;
    const int t = threadIdx.x;
    const int w = t >> 6, l = t & 63, g = l >> 4, ln = l & 15;
    const int nb = blockIdx.x * 128 + 32 * w;
    char* wl = lds + w * 8192;          // wave-private, 2 x 4 KB

    const char* wqk = ws + WQK_OFF + b * 65536;
    const float* xb = x + (size_t)b * CIN * NPIX + nb;

    const int n4 = 4 * (l & 7);
    const int cg0 = (l >> 3);

    f32x4 xr[2][4];

#define STAGE_LOAD(S)                                                          \
    {                                                                          \
        _Pragma("unroll")                                                      \
        for (int u = 0; u < 2; ++u) {                                          \
            const float* xp = xb + (size_t)(64 * (S) + 4 * (cg0 + 8 * u)) * NPIX + n4; \
            _Pragma("unroll")                                                  \
            for (int i = 0; i < 4; ++i)                                        \
                xr[u][i] = *(const f32x4*)(xp + (size_t)i * NPIX);             \
        }                                                                      \
    }

#define STAGE_WRITE(BUF)                                                       \
    {                                                                          \
        _Pragma("unroll")                                                      \
        for (int u = 0; u < 2; ++u) {                                          \
            int cg = cg0 + 8 * u;                                              \
            _Pragma("unroll")                                                  \
            for (int j = 0; j < 4; ++j) {                                      \
                f16x4 v4;                                                      \
                v4[0] = (f16)xr[u][0][j]; v4[1] = (f16)xr[u][1][j];            \
                v4[2] = (f16)xr[u][2][j]; v4[3] = (f16)xr[u][3][j];            \
                int nl = n4 + j;                                               \
                int fn = (nl ^ (nl >> 3)) & 7;                                 \
                *(f16x4*)((BUF) + nl * 128 + 16 * ((cg >> 1) ^ fn) + 8 * (cg & 1)) = v4; \
            }                                                                  \
        }                                                                      \
    }

    // ---- sim: 8 c-chunks of 64, wave-private pipeline, no barriers ----
    f32x4 accs[2][4] = {};   // [nt][mi]
    STAGE_LOAD(0);
    STAGE_WRITE(wl);
    #pragma unroll
    for (int s = 0; s < 8; ++s) {
        const char* cur = wl + (s & 1) * 4096;
        if (s < 7) STAGE_LOAD(s + 1);
        #pragma unroll
        for (int kk = 0; kk < 2; ++kk) {
            f16x8 bf[2];
            #pragma unroll
            for (int nt = 0; nt < 2; ++nt) {
                int nl = 16 * nt + ln;
                int fn = (nl ^ (nl >> 3)) & 7;
                bf[nt] = *(const f16x8*)(cur + nl * 128 + 16 * ((4 * kk + g) ^ fn));
            }
            #pragma unroll
            for (int mi = 0; mi < 4; ++mi) {
                f16x8 af = *(const f16x8*)(wqk + ((((s * 4 + mi) * 2 + kk) * 4 + g) * 16 + ln) * 16);
                accs[0][mi] = __builtin_amdgcn_mfma_f32_16x16x32_f16(af, bf[0], accs[0][mi], 0, 0, 0);
                accs[1][mi] = __builtin_amdgcn_mfma_f32_16x16x32_f16(af, bf[1], accs[1][mi], 0, 0, 0);
            }
        }
        if (s < 7) STAGE_WRITE(wl + ((s + 1) & 1) * 4096);
    }

    // ---- softmax over m (64) per n-tile; store attn in A-frag order ----
    #pragma unroll
    for (int nt = 0; nt < 2; ++nt) {
        float mx = accs[nt][0][0];
        #pragma unroll
        for (int mi = 0; mi < 4; ++mi)
            #pragma unroll
            for (int r = 0; r < 4; ++r) mx = fmaxf(mx, accs[nt][mi][r]);
        mx = fmaxf(mx, __shfl_xor(mx, 16, 64));
        mx = fmaxf(mx, __shfl_xor(mx, 32, 64));
        float pv[4][4];
        float sum = 0.f;
        #pragma unroll
        for (int mi = 0; mi < 4; ++mi)
            #pragma unroll
            for (int r = 0; r < 4; ++r) {
                float pe = __builtin_amdgcn_exp2f((accs[nt][mi][r] - mx) * LOG2E);
                pv[mi][r] = pe; sum += pe;
            }
        sum += __shfl_xor(sum, 16, 64);
        sum += __shfl_xor(sum, 32, 64);
        float inv = 1.f / sum;
        // A-frag order: element j of half kk = m = 32kk + 16(j>>2) + 4g + (j&3)
        const int n = nb + 16 * nt + ln;
        char* ap = attn + ((size_t)b * NPIX + n) * 128 + 16 * g;
        #pragma unroll
        for (int kk = 0; kk < 2; ++kk) {
            f16x8 afr;
            #pragma unroll
            for (int j = 0; j < 8; ++j)
                afr[j] = (f16)(pv[2 * kk + (j >> 2)][j & 3] * inv);
            *(f16x8*)(ap + kk * 64) = afr;
        }
    }
}

// ---------------------------------------------------------------------------
// outk: write-bound half. 256 threads = 4 waves, each owns 16 px. NO LDS,
// no barriers, ~50 VGPR -> 8 blocks/CU = 32 free-running waves.
//   afr = attn A-frags straight from global (16 B/lane, L2/L3-hot);
//   B-frags = Wpv frag table (1 KB/instr, L2-hot); f32x4 out stores.
// ---------------------------------------------------------------------------
__global__ __launch_bounds__(256, 8) void outk(const char* __restrict__ attn,
                                               const char* __restrict__ ws,
                                               float* __restrict__ out) {
    const int b = blockIdx.y;
    const int t = threadIdx.x;
    const int w = t >> 6, l = t & 63, g = l >> 4, ln = l & 15;
    const int nb = blockIdx.x * 64 + 16 * w;

    const char* wpv = ws + WPV_OFF + b * 65536;
    const char* ap = attn + ((size_t)b * NPIX + nb + ln) * 128 + 16 * g;

    f16x8 afr[2];
    afr[0] = *(const f16x8*)(ap);
    afr[1] = *(const f16x8*)(ap + 64);

    float* ob = out + (size_t)b * CIN * NPIX + nb + 4 * g;
    #pragma unroll 4
    for (int ct = 0; ct < 32; ++ct) {
        int c = 16 * ct + ln;
        f32x4 acc = {};
        #pragma unroll
        for (int kk = 0; kk < 2; ++kk) {
            f16x8 bfp = *(const f16x8*)(wpv + (((ct * 2 + kk) * 4 + g) * 16 + ln) * 16);
            acc = __builtin_amdgcn_mfma_f32_16x16x32_f16(afr[kk], bfp, acc, 0, 0, 0);
        }
        *(f32x4*)(ob + (size_t)c * NPIX) = acc;
    }
}

// ---------------------------------------------------------------------------
extern "C" void kernel_launch(void* const* d_in, const int* in_sizes, int n_in,
                              void* d_out, int out_size, void* d_ws, size_t ws_size,
                              hipStream_t stream) {
    (void)in_sizes; (void)n_in; (void)out_size; (void)ws_size;
    const float* x   = (const float*)d_in[0];
    const float* ctx = (const float*)d_in[1];
    const float* Wq  = (const float*)d_in[2];
    const float* Wk  = (const float*)d_in[3];
    const float* Wv  = (const float*)d_in[4];
    const float* Wp  = (const float*)d_in[5];
    float* out = (float*)d_out;
    char* ws = (char*)d_ws;

    prep<<<dim3(4, B_), 1024, 0, stream>>>(ctx, Wk, Wv, Wq, Wp, ws);
    simk<<<dim3(NPIX / 128, B_), 256, 0, stream>>>(x, ws, ws + ATTN_OFF);
    outk<<<dim3(NPIX / 64, B_), 256, 0, stream>>>(ws + ATTN_OFF, ws, out);
}

// Round 13
// 180.765 us; speedup vs baseline: 1.0710x; 1.0710x over previous
//
#include <hip/hip_runtime.h>
#include <stdint.h>

// Problem constants
#define B_    8
#define CIN   512
#define NPIX  16384
#define CK    256
#define KCTX  64
#define CV    256

typedef _Float16 f16;
typedef _Float16 f16x4 __attribute__((ext_vector_type(4)));
typedef _Float16 f16x8 __attribute__((ext_vector_type(8)));
typedef float    f32x4 __attribute__((ext_vector_type(4)));

#define LOG2E 1.44269504f

// ws layout (bytes). Tables in exact MFMA fragment order (verified rounds 6-12).
// WQK: A-frag for sim.  byte = ((((s*4+mi)*2+kk)*4+g)*16+ln)*16 + 2*j
//      holds Wqk^T(c,m)*1/16 with c = 64s+32kk+8g+j, m = 16mi+ln
// WPV: B-frag for out.  byte = (((ct*2+kk)*4+g)*16+lnc)*16 + 2*j
//      holds Wpv(c,m) with c = 16ct+lnc, m = 16*(2kk+(j>>2))+4g+(j&3)
#define WQK_OFF  0           // 512 KB : [b][64 KB]
#define WPV_OFF  524288      // 512 KB : [b][64 KB]

#define WAITVM(N) asm volatile("s_waitcnt vmcnt(" #N ")" ::: "memory")
#define LGKM0     asm volatile("s_waitcnt lgkmcnt(0)" ::: "memory")
#define SCHEDB    __builtin_amdgcn_sched_barrier(0)
#define SBAR      __builtin_amdgcn_s_barrier()

__device__ __forceinline__ void gl_lds16(const void* g, void* l) {
    __builtin_amdgcn_global_load_lds(
        (const __attribute__((address_space(1))) uint32_t*)g,
        (__attribute__((address_space(3))) uint32_t*)l, 16, 0, 0);
}

// ---------------------------------------------------------------------------
// prep: grid (4, B), 1024 threads, 64 KB LDS.  (unchanged from rounds 6-12)
// ---------------------------------------------------------------------------
__global__ __launch_bounds__(1024) void prep(const float* __restrict__ ctx,
                                             const float* __restrict__ Wk,
                                             const float* __restrict__ Wv,
                                             const float* __restrict__ Wq,
                                             const float* __restrict__ Wp,
                                             char* __restrict__ ws) {
    __shared__ char lds[65536];
    char* ctx_t = lds;              // 32 KB
    char* kv_s  = lds + 32768;      // 32 KB

    const int p = blockIdx.x;
    const int b = blockIdx.y;
    const int path = p >> 1, h = p & 1;
    const int t = threadIdx.x;
    const int w = t >> 6, l = t & 63, g = l >> 4, ln = l & 15;

    // ---- stage ctx transposed: ctx_t[m][c] f16 swz ----
    {
        const int m4 = (t & 15) * 4, c4 = (t >> 4) * 4;
        const float* cp = ctx + (size_t)b * (CV * KCTX) + (size_t)c4 * KCTX + m4;
        f32x4 xr[4];
        #pragma unroll
        for (int i = 0; i < 4; ++i) xr[i] = *(const f32x4*)(cp + (size_t)i * KCTX);
        #pragma unroll
        for (int j = 0; j < 4; ++j) {
            f16x4 v4; v4[0] = (f16)xr[0][j]; v4[1] = (f16)xr[1][j]; v4[2] = (f16)xr[2][j]; v4[3] = (f16)xr[3][j];
            int m = m4 + j;
            *(f16x4*)(ctx_t + m * 512 + 16 * (((c4 >> 3) & 31) ^ (m & 7)) + 2 * (c4 & 7)) = v4;
        }
    }
    __syncthreads();

    // ---- kv GEMM: D[row][m] = (path? Wv : Wk) * ctx, K=256 ----
    {
        const float* W = path ? Wv : Wk;
        const int rbase = 64 * (w >> 2);
        const int mm = 16 * (w & 3) + ln;
        f32x4 acc[4] = {};
        for (int ks = 0; ks < 8; ++ks) {
            f16x8 bf = *(const f16x8*)(ctx_t + mm * 512 + 16 * ((4 * ks + g) ^ (mm & 7)));
            #pragma unroll
            for (int mi = 0; mi < 4; ++mi) {
                int row = rbase + 16 * mi + ln;
                const float* wp0 = W + (size_t)row * CV + 32 * ks + 8 * g;
                f32x4 lo = *(const f32x4*)wp0, hi = *(const f32x4*)(wp0 + 4);
                f16x8 af;
                #pragma unroll
                for (int j = 0; j < 4; ++j) { af[j] = (f16)lo[j]; af[4 + j] = (f16)hi[j]; }
                acc[mi] = __builtin_amdgcn_mfma_f32_16x16x32_f16(af, bf, acc[mi], 0, 0, 0);
            }
        }
        #pragma unroll
        for (int mi = 0; mi < 4; ++mi)
            #pragma unroll
            for (int r = 0; r < 4; ++r) {
                int row = rbase + 16 * mi + 4 * g + r;
                *(f16*)(kv_s + mm * 512 + 16 * ((((row >> 3) & 31)) ^ (mm & 7)) + 2 * (row & 7)) = (f16)acc[mi][r];
            }
    }
    __syncthreads();

    if (path == 0) {
        // ---- Wqk^T[c][m] = sum_kk Wq[kk][c] k[kk][m]; A gathered from global ----
        f32x4 acc2[4] = {};
        const int cA = 256 * h + 16 * w + ln;
        const float* qcol = Wq + cA;
        for (int ks = 0; ks < 8; ++ks) {
            f16x8 af;
            #pragma unroll
            for (int j = 0; j < 8; ++j)
                af[j] = (f16)qcol[(size_t)(32 * ks + 8 * g + j) * CIN];
            #pragma unroll
            for (int ni = 0; ni < 4; ++ni) {
                int m2 = 16 * ni + ln;
                f16x8 bf = *(const f16x8*)(kv_s + m2 * 512 + 16 * ((4 * ks + g) ^ (m2 & 7)));
                acc2[ni] = __builtin_amdgcn_mfma_f32_16x16x32_f16(af, bf, acc2[ni], 0, 0, 0);
            }
        }
        char* dst = ws + WQK_OFF + b * 65536;
        #pragma unroll
        for (int ni = 0; ni < 4; ++ni)
            #pragma unroll
            for (int r = 0; r < 4; ++r) {
                int c = 256 * h + 16 * w + 4 * g + r;     // k-dim index of sim GEMM
                int s  = c >> 6, kk = (c >> 5) & 1, gk = (c >> 3) & 3, j = c & 7;
                int byte = ((((s * 4 + ni) * 2 + kk) * 4 + gk) * 16 + ln) * 16 + 2 * j;
                *(f16*)(dst + byte) = (f16)(acc2[ni][r] * 0.0625f);   // fold scale 1/16
            }
    } else {
        // ---- Wpv[c][m] = sum_v Wp[c][v] v[v][m]; A direct from global ----
        f32x4 acc2[4] = {};
        const int cA = 256 * h + 16 * w + ln;
        for (int ks = 0; ks < 8; ++ks) {
            const float* pp = Wp + (size_t)cA * CV + 32 * ks + 8 * g;
            f32x4 lo = *(const f32x4*)pp, hi = *(const f32x4*)(pp + 4);
            f16x8 af;
            #pragma unroll
            for (int j = 0; j < 4; ++j) { af[j] = (f16)lo[j]; af[4 + j] = (f16)hi[j]; }
            #pragma unroll
            for (int ni = 0; ni < 4; ++ni) {
                int m2 = 16 * ni + ln;
                f16x8 bf = *(const f16x8*)(kv_s + m2 * 512 + 16 * ((4 * ks + g) ^ (m2 & 7)));
                acc2[ni] = __builtin_amdgcn_mfma_f32_16x16x32_f16(af, bf, acc2[ni], 0, 0, 0);
            }
        }
        char* dst = ws + WPV_OFF + b * 65536;
        #pragma unroll
        for (int ni = 0; ni < 4; ++ni) {
            const int kkm = ni >> 1;
            const int gm  = ln >> 2;
            const int jm  = 4 * (ni & 1) + (ln & 3);
            #pragma unroll
            for (int r = 0; r < 4; ++r) {
                int c = 256 * h + 16 * w + 4 * g + r;     // output-channel index
                int ct = c >> 4, lnc = c & 15;
                int byte = (((ct * 2 + kkm) * 4 + gm) * 16 + lnc) * 16 + 2 * jm;
                *(f16*)(dst + byte) = (f16)acc2[ni][r];
            }
        }
    }
}

// ---------------------------------------------------------------------------
// fused: 1024 threads = 16 waves, 512-px n-tile, 1 block/CU (128 KB dyn LDS).
// ALL global row-segments >= 2 KB; every wave-load = 1 KB contiguous.
//  - Wqk staged once in LDS (VMEM queue in K-loop = only my asm x loads).
//  - x dbuf [512 n][32 c] f16 swz (64 B rows), 16 chunks, depth-2 asm
//    prefetch, counted vmcnt, ONE barrier/chunk.
//  - attn in registers; Wpv re-staged over x region; out = 2 KB/row/block.
// ---------------------------------------------------------------------------
__global__ __launch_bounds__(1024) void fused(const float* __restrict__ x,
                                              const char* __restrict__ ws,
                                              float* __restrict__ out) {
    extern __shared__ char lds[];              // 128 KB dynamic
    char* wqk_l = lds;                         // 64 KB: Wqk frag table
    char* x_s   = lds + 65536;                 // 2 x 32 KB [512 n][32 c] f16 swz
    char* wpv_l = lds + 65536;                 // reused for Wpv in out phase

    const int b  = blockIdx.y;
    const int n0 = blockIdx.x * 512;
    const int t  = threadIdx.x;
    const int w  = t >> 6, l = t & 63, g = l >> 4, ln = l & 15;

    const char* wqk_g = ws + WQK_OFF + b * 65536;
    const char* wpv_g = ws + WPV_OFF + b * 65536;
    const float* xb = x + (size_t)b * CIN * NPIX + n0;

    // staging: thread t -> n4 = 4*(t&127) (512 n / wave = 1 KB contiguous),
    // rows c = 4*(t>>7) + i (i=0..3) of the 32-c chunk.
    const int n4 = 4 * (t & 127);
    const int u  = t >> 7;                 // 0..7
    const int rowbase = 4 * u;
    const int wslot_hi = u >> 1;           // c>>3 of this thread's 4 rows
    const int wslot_lo = 8 * (u & 1);      // byte offset of c&7 base

    f32x4 xr[2][4];

#define STAGE_LOAD(S, SLOT)                                                    \
    {                                                                          \
        const float* xp = xb + (size_t)(32 * (S) + rowbase) * NPIX + n4;       \
        asm volatile("global_load_dwordx4 %0, %1, off"                        \
                     : "=&v"(xr[SLOT][0]) : "v"(xp));                          \
        asm volatile("global_load_dwordx4 %0, %1, off"                        \
                     : "=&v"(xr[SLOT][1]) : "v"(xp + NPIX));                   \
        asm volatile("global_load_dwordx4 %0, %1, off"                        \
                     : "=&v"(xr[SLOT][2]) : "v"(xp + 2 * (size_t)NPIX));       \
        asm volatile("global_load_dwordx4 %0, %1, off"                        \
                     : "=&v"(xr[SLOT][3]) : "v"(xp + 3 * (size_t)NPIX));       \
    }

    // LDS x layout: byte(n, c) = n*64 + 16*(((c>>3) ^ fn2(n)) & 3) + 2*(c&7),
    // fn2(n) = (n ^ (n>>2)) & 3. Write packs c = rowbase..rowbase+3.
#define STAGE_WRITE(BUF, SLOT)                                                 \
    {                                                                          \
        _Pragma("unroll")                                                      \
        for (int j = 0; j < 4; ++j) {                                          \
            f16x4 v4;                                                          \
            v4[0] = (f16)xr[SLOT][0][j]; v4[1] = (f16)xr[SLOT][1][j];          \
            v4[2] = (f16)xr[SLOT][2][j]; v4[3] = (f16)xr[SLOT][3][j];          \
            int nl = n4 + j;                                                   \
            int fn2 = (nl ^ (nl >> 2)) & 3;                                    \
            *(f16x4*)((BUF) + nl * 64 + 16 * ((wslot_hi ^ fn2) & 3) + wslot_lo) = v4; \
        }                                                                      \
    }

    // ---- prologue: Wqk table (4 gl_lds) + x0,x1 (4+4 asm loads) ----
    #pragma unroll
    for (int r = 0; r < 4; ++r) {
        int ch = t + 1024 * r;
        gl_lds16(wqk_g + ch * 16, wqk_l + ch * 16);
    }
    SCHEDB;
    STAGE_LOAD(0, 0); SCHEDB;
    STAGE_LOAD(1, 1); SCHEDB;
    WAITVM(4);   // retire wqk-stage + x0; x1 (4) outstanding
    SCHEDB;
    STAGE_WRITE(x_s, 0);
    LGKM0; SCHEDB; SBAR; SCHEDB;

    // ---- sim: 16 c-chunks of 32; ONE barrier/chunk; depth-2 prefetch ----
    f32x4 accs[2][4] = {};   // [nt][mi]; n = n0+32w+16nt+ln, m = 16mi+4g+r
    #pragma unroll
    for (int cc = 0; cc < 16; ++cc) {
        const char* xc = x_s + (cc & 1) * 32768;
        f16x8 bf[2];
        #pragma unroll
        for (int nt = 0; nt < 2; ++nt) {
            int nl = 32 * w + 16 * nt + ln;
            int fn2 = (nl ^ (nl >> 2)) & 3;
            bf[nt] = *(const f16x8*)(xc + nl * 64 + 16 * ((g ^ fn2) & 3));
        }
        #pragma unroll
        for (int mi = 0; mi < 4; ++mi) {
            f16x8 af = *(const f16x8*)(wqk_l +
                ((((cc >> 1) * 4 + mi) * 2 + (cc & 1)) * 4 + g) * 256 + ln * 16);
            accs[0][mi] = __builtin_amdgcn_mfma_f32_16x16x32_f16(af, bf[0], accs[0][mi], 0, 0, 0);
            accs[1][mi] = __builtin_amdgcn_mfma_f32_16x16x32_f16(af, bf[1], accs[1][mi], 0, 0, 0);
        }
        SCHEDB;
        if (cc < 14) { STAGE_LOAD(cc + 2, cc & 1); SCHEDB; }
        if (cc < 15) {
            if (cc < 14) { WAITVM(4); } else { WAITVM(0); }
            SCHEDB;
            STAGE_WRITE(x_s + ((cc + 1) & 1) * 32768, (cc + 1) & 1);
            LGKM0; SCHEDB; SBAR; SCHEDB;
        }
    }
    LGKM0; SCHEDB; SBAR; SCHEDB;   // all x reads done before Wpv overwrites

    // ---- stage Wpv over x region; softmax overlaps ----
    #pragma unroll
    for (int r = 0; r < 4; ++r) {
        int ch = t + 1024 * r;
        gl_lds16(wpv_g + ch * 16, wpv_l + ch * 16);
    }

    // ---- softmax over m (64) per n-tile, in-register ----
    f16x8 afr[2][2];   // [nt][kk]
    #pragma unroll
    for (int nt = 0; nt < 2; ++nt) {
        float mx = accs[nt][0][0];
        #pragma unroll
        for (int mi = 0; mi < 4; ++mi)
            #pragma unroll
            for (int r = 0; r < 4; ++r) mx = fmaxf(mx, accs[nt][mi][r]);
        mx = fmaxf(mx, __shfl_xor(mx, 16, 64));
        mx = fmaxf(mx, __shfl_xor(mx, 32, 64));
        float pv[4][4];
        float sum = 0.f;
        #pragma unroll
        for (int mi = 0; mi < 4; ++mi)
            #pragma unroll
            for (int r = 0; r < 4; ++r) {
                float pe = __builtin_amdgcn_exp2f((accs[nt][mi][r] - mx) * LOG2E);
                pv[mi][r] = pe; sum += pe;
            }
        sum += __shfl_xor(sum, 16, 64);
        sum += __shfl_xor(sum, 32, 64);
        float inv = 1.f / sum;
        // attn A-frags: (kk,g,j) -> m = 16*(2kk+(j>>2)) + 4g + (j&3)
        #pragma unroll
        for (int kk = 0; kk < 2; ++kk)
            #pragma unroll
            for (int j = 0; j < 8; ++j)
                afr[nt][kk][j] = (f16)(pv[2 * kk + (j >> 2)][j & 3] * inv);
    }
    WAITVM(0); SCHEDB; SBAR; SCHEDB;   // Wpv staged for all waves

    // ---- out: 32 c-tiles; B-frags from LDS; 2 KB contiguous per row/block --
    float* ob = out + (size_t)b * CIN * NPIX + n0 + 32 * w + 4 * g;
    #pragma unroll 4
    for (int ct = 0; ct < 32; ++ct) {
        int c = 16 * ct + ln;
        f32x4 a0 = {}, a1 = {};
        #pragma unroll
        for (int kk = 0; kk < 2; ++kk) {
            f16x8 bfp = *(const f16x8*)(wpv_l + (((ct * 2 + kk) * 4 + g) * 16 + ln) * 16);
            a0 = __builtin_amdgcn_mfma_f32_16x16x32_f16(afr[0][kk], bfp, a0, 0, 0, 0);
            a1 = __builtin_amdgcn_mfma_f32_16x16x32_f16(afr[1][kk], bfp, a1, 0, 0, 0);
        }
        *(f32x4*)(ob + (size_t)c * NPIX)      = a0;
        *(f32x4*)(ob + (size_t)c * NPIX + 16) = a1;
    }
}

// ---------------------------------------------------------------------------
extern "C" void kernel_launch(void* const* d_in, const int* in_sizes, int n_in,
                              void* d_out, int out_size, void* d_ws, size_t ws_size,
                              hipStream_t stream) {
    (void)in_sizes; (void)n_in; (void)out_size; (void)ws_size;
    const float* x   = (const float*)d_in[0];
    const float* ctx = (const float*)d_in[1];
    const float* Wq  = (const float*)d_in[2];
    const float* Wk  = (const float*)d_in[3];
    const float* Wv  = (const float*)d_in[4];
    const float* Wp  = (const float*)d_in[5];
    float* out = (float*)d_out;
    char* ws = (char*)d_ws;

    prep<<<dim3(4, B_), 1024, 0, stream>>>(ctx, Wk, Wv, Wq, Wp, ws);
    fused<<<dim3(NPIX / 512, B_), 1024, 131072, stream>>>(x, ws, out);
}

// Round 14
// 177.675 us; speedup vs baseline: 1.0896x; 1.0174x over previous
//
#include <hip/hip_runtime.h>
#include <stdint.h>

// Problem constants
#define B_    8
#define CIN   512
#define NPIX  16384
#define CK    256
#define KCTX  64
#define CV    256

typedef _Float16 f16;
typedef _Float16 f16x4 __attribute__((ext_vector_type(4)));
typedef _Float16 f16x8 __attribute__((ext_vector_type(8)));
typedef float    f32x4 __attribute__((ext_vector_type(4)));

#define LOG2E 1.44269504f

// ws layout (bytes). Tables in exact MFMA fragment order (verified rounds 6-13).
// WQK: A-frag for sim.  byte = ((((s*4+mi)*2+kk)*4+g)*16+ln)*16 + 2*j
//      holds Wqk^T(c,m)*1/16 with c = 64s+32kk+8g+j, m = 16mi+ln
// WPV: B-frag for out.  byte = (((ct*2+kk)*4+g)*16+lnc)*16 + 2*j
//      holds Wpv(c,m) with c = 16ct+lnc, m = 16*(2kk+(j>>2))+4g+(j&3)
// ATTN: A-frag for out. byte = n*128 + kk*64 + 16*g + 2*j
//      holds attn(n,m) f16 with m = 32kk + 16*(j>>2) + 4g + (j&3)
#define WQK_OFF  0           // 512 KB : [b][64 KB]
#define WPV_OFF  524288      // 512 KB : [b][64 KB]
#define ATTN_OFF 1048576     // 16.8 MB: [b][n][128 B]

__device__ __forceinline__ void gl_lds16(const void* g, void* l) {
    __builtin_amdgcn_global_load_lds(
        (const __attribute__((address_space(1))) uint32_t*)g,
        (__attribute__((address_space(3))) uint32_t*)l, 16, 0, 0);
}

// ---------------------------------------------------------------------------
// prep: grid (4, B), 1024 threads, 64 KB LDS.  (unchanged, verified)
// ---------------------------------------------------------------------------
__global__ __launch_bounds__(1024) void prep(const float* __restrict__ ctx,
                                             const float* __restrict__ Wk,
                                             const float* __restrict__ Wv,
                                             const float* __restrict__ Wq,
                                             const float* __restrict__ Wp,
                                             char* __restrict__ ws) {
    __shared__ char lds[65536];
    char* ctx_t = lds;              // 32 KB
    char* kv_s  = lds + 32768;      // 32 KB

    const int p = blockIdx.x;
    const int b = blockIdx.y;
    const int path = p >> 1, h = p & 1;
    const int t = threadIdx.x;
    const int w = t >> 6, l = t & 63, g = l >> 4, ln = l & 15;

    // ---- stage ctx transposed: ctx_t[m][c] f16 swz ----
    {
        const int m4 = (t & 15) * 4, c4 = (t >> 4) * 4;
        const float* cp = ctx + (size_t)b * (CV * KCTX) + (size_t)c4 * KCTX + m4;
        f32x4 xr[4];
        #pragma unroll
        for (int i = 0; i < 4; ++i) xr[i] = *(const f32x4*)(cp + (size_t)i * KCTX);
        #pragma unroll
        for (int j = 0; j < 4; ++j) {
            f16x4 v4; v4[0] = (f16)xr[0][j]; v4[1] = (f16)xr[1][j]; v4[2] = (f16)xr[2][j]; v4[3] = (f16)xr[3][j];
            int m = m4 + j;
            *(f16x4*)(ctx_t + m * 512 + 16 * (((c4 >> 3) & 31) ^ (m & 7)) + 2 * (c4 & 7)) = v4;
        }
    }
    __syncthreads();

    // ---- kv GEMM: D[row][m] = (path? Wv : Wk) * ctx, K=256 ----
    {
        const float* W = path ? Wv : Wk;
        const int rbase = 64 * (w >> 2);
        const int mm = 16 * (w & 3) + ln;
        f32x4 acc[4] = {};
        for (int ks = 0; ks < 8; ++ks) {
            f16x8 bf = *(const f16x8*)(ctx_t + mm * 512 + 16 * ((4 * ks + g) ^ (mm & 7)));
            #pragma unroll
            for (int mi = 0; mi < 4; ++mi) {
                int row = rbase + 16 * mi + ln;
                const float* wp0 = W + (size_t)row * CV + 32 * ks + 8 * g;
                f32x4 lo = *(const f32x4*)wp0, hi = *(const f32x4*)(wp0 + 4);
                f16x8 af;
                #pragma unroll
                for (int j = 0; j < 4; ++j) { af[j] = (f16)lo[j]; af[4 + j] = (f16)hi[j]; }
                acc[mi] = __builtin_amdgcn_mfma_f32_16x16x32_f16(af, bf, acc[mi], 0, 0, 0);
            }
        }
        #pragma unroll
        for (int mi = 0; mi < 4; ++mi)
            #pragma unroll
            for (int r = 0; r < 4; ++r) {
                int row = rbase + 16 * mi + 4 * g + r;
                *(f16*)(kv_s + mm * 512 + 16 * ((((row >> 3) & 31)) ^ (mm & 7)) + 2 * (row & 7)) = (f16)acc[mi][r];
            }
    }
    __syncthreads();

    if (path == 0) {
        f32x4 acc2[4] = {};
        const int cA = 256 * h + 16 * w + ln;
        const float* qcol = Wq + cA;
        for (int ks = 0; ks < 8; ++ks) {
            f16x8 af;
            #pragma unroll
            for (int j = 0; j < 8; ++j)
                af[j] = (f16)qcol[(size_t)(32 * ks + 8 * g + j) * CIN];
            #pragma unroll
            for (int ni = 0; ni < 4; ++ni) {
                int m2 = 16 * ni + ln;
                f16x8 bf = *(const f16x8*)(kv_s + m2 * 512 + 16 * ((4 * ks + g) ^ (m2 & 7)));
                acc2[ni] = __builtin_amdgcn_mfma_f32_16x16x32_f16(af, bf, acc2[ni], 0, 0, 0);
            }
        }
        char* dst = ws + WQK_OFF + b * 65536;
        #pragma unroll
        for (int ni = 0; ni < 4; ++ni)
            #pragma unroll
            for (int r = 0; r < 4; ++r) {
                int c = 256 * h + 16 * w + 4 * g + r;
                int s  = c >> 6, kk = (c >> 5) & 1, gk = (c >> 3) & 3, j = c & 7;
                int byte = ((((s * 4 + ni) * 2 + kk) * 4 + gk) * 16 + ln) * 16 + 2 * j;
                *(f16*)(dst + byte) = (f16)(acc2[ni][r] * 0.0625f);
            }
    } else {
        f32x4 acc2[4] = {};
        const int cA = 256 * h + 16 * w + ln;
        for (int ks = 0; ks < 8; ++ks) {
            const float* pp = Wp + (size_t)cA * CV + 32 * ks + 8 * g;
            f32x4 lo = *(const f32x4*)pp, hi = *(const f32x4*)(pp + 4);
            f16x8 af;
            #pragma unroll
            for (int j = 0; j < 4; ++j) { af[j] = (f16)lo[j]; af[4 + j] = (f16)hi[j]; }
            #pragma unroll
            for (int ni = 0; ni < 4; ++ni) {
                int m2 = 16 * ni + ln;
                f16x8 bf = *(const f16x8*)(kv_s + m2 * 512 + 16 * ((4 * ks + g) ^ (m2 & 7)));
                acc2[ni] = __builtin_amdgcn_mfma_f32_16x16x32_f16(af, bf, acc2[ni], 0, 0, 0);
            }
        }
        char* dst = ws + WPV_OFF + b * 65536;
        #pragma unroll
        for (int ni = 0; ni < 4; ++ni) {
            const int kkm = ni >> 1;
            const int gm  = ln >> 2;
            const int jm  = 4 * (ni & 1) + (ln & 3);
            #pragma unroll
            for (int r = 0; r < 4; ++r) {
                int c = 256 * h + 16 * w + 4 * g + r;
                int ct = c >> 4, lnc = c & 15;
                int byte = (((ct * 2 + kkm) * 4 + gm) * 16 + lnc) * 16 + 2 * jm;
                *(f16*)(dst + byte) = (f16)acc2[ni][r];
            }
        }
    }
}

// ---------------------------------------------------------------------------
// simk: read half, unchanged from round 12 (verified).
// ---------------------------------------------------------------------------
__global__ __launch_bounds__(256, 4) void simk(const float* __restrict__ x,
                                               const char* __restrict__ ws,
                                               char* __restrict__ attn) {
    __shared__ char lds[32768];
    const int b = blockIdx.y;
    const int t = threadIdx.x;
    const int w = t >> 6, l = t & 63, g = l >> 4, ln = l & 15;
    const int nb = blockIdx.x * 128 + 32 * w;
    char* wl = lds + w * 8192;          // wave-private, 2 x 4 KB

    const char* wqk = ws + WQK_OFF + b * 65536;
    const float* xb = x + (size_t)b * CIN * NPIX + nb;

    const int n4 = 4 * (l & 7);
    const int cg0 = (l >> 3);

    f32x4 xr[2][4];

#define STAGE_LOAD(S)                                                          \
    {                                                                          \
        _Pragma("unroll")                                                      \
        for (int u = 0; u < 2; ++u) {                                          \
            const float* xp = xb + (size_t)(64 * (S) + 4 * (cg0 + 8 * u)) * NPIX + n4; \
            _Pragma("unroll")                                                  \
            for (int i = 0; i < 4; ++i)                                        \
                xr[u][i] = *(const f32x4*)(xp + (size_t)i * NPIX);             \
        }                                                                      \
    }

#define STAGE_WRITE(BUF)                                                       \
    {                                                                          \
        _Pragma("unroll")                                                      \
        for (int u = 0; u < 2; ++u) {                                          \
            int cg = cg0 + 8 * u;                                              \
            _Pragma("unroll")                                                  \
            for (int j = 0; j < 4; ++j) {                                      \
                f16x4 v4;                                                      \
                v4[0] = (f16)xr[u][0][j]; v4[1] = (f16)xr[u][1][j];            \
                v4[2] = (f16)xr[u][2][j]; v4[3] = (f16)xr[u][3][j];            \
                int nl = n4 + j;                                               \
                int fn = (nl ^ (nl >> 3)) & 7;                                 \
                *(f16x4*)((BUF) + nl * 128 + 16 * ((cg >> 1) ^ fn) + 8 * (cg & 1)) = v4; \
            }                                                                  \
        }                                                                      \
    }

    f32x4 accs[2][4] = {};   // [nt][mi]
    STAGE_LOAD(0);
    STAGE_WRITE(wl);
    #pragma unroll
    for (int s = 0; s < 8; ++s) {
        const char* cur = wl + (s & 1) * 4096;
        if (s < 7) STAGE_LOAD(s + 1);
        #pragma unroll
        for (int kk = 0; kk < 2; ++kk) {
            f16x8 bf[2];
            #pragma unroll
            for (int nt = 0; nt < 2; ++nt) {
                int nl = 16 * nt + ln;
                int fn = (nl ^ (nl >> 3)) & 7;
                bf[nt] = *(const f16x8*)(cur + nl * 128 + 16 * ((4 * kk + g) ^ fn));
            }
            #pragma unroll
            for (int mi = 0; mi < 4; ++mi) {
                f16x8 af = *(const f16x8*)(wqk + ((((s * 4 + mi) * 2 + kk) * 4 + g) * 16 + ln) * 16);
                accs[0][mi] = __builtin_amdgcn_mfma_f32_16x16x32_f16(af, bf[0], accs[0][mi], 0, 0, 0);
                accs[1][mi] = __builtin_amdgcn_mfma_f32_16x16x32_f16(af, bf[1], accs[1][mi], 0, 0, 0);
            }
        }
        if (s < 7) STAGE_WRITE(wl + ((s + 1) & 1) * 4096);
    }

    #pragma unroll
    for (int nt = 0; nt < 2; ++nt) {
        float mx = accs[nt][0][0];
        #pragma unroll
        for (int mi = 0; mi < 4; ++mi)
            #pragma unroll
            for (int r = 0; r < 4; ++r) mx = fmaxf(mx, accs[nt][mi][r]);
        mx = fmaxf(mx, __shfl_xor(mx, 16, 64));
        mx = fmaxf(mx, __shfl_xor(mx, 32, 64));
        float pv[4][4];
        float sum = 0.f;
        #pragma unroll
        for (int mi = 0; mi < 4; ++mi)
            #pragma unroll
            for (int r = 0; r < 4; ++r) {
                float pe = __builtin_amdgcn_exp2f((accs[nt][mi][r] - mx) * LOG2E);
                pv[mi][r] = pe; sum += pe;
            }
        sum += __shfl_xor(sum, 16, 64);
        sum += __shfl_xor(sum, 32, 64);
        float inv = 1.f / sum;
        const int n = nb + 16 * nt + ln;
        char* ap = attn + ((size_t)b * NPIX + n) * 128 + 16 * g;
        #pragma unroll
        for (int kk = 0; kk < 2; ++kk) {
            f16x8 afr;
            #pragma unroll
            for (int j = 0; j < 8; ++j)
                afr[j] = (f16)(pv[2 * kk + (j >> 2)][j & 3] * inv);
            *(f16x8*)(ap + kk * 64) = afr;
        }
    }
}

// ---------------------------------------------------------------------------
// outk v2: write half with 1 KB CONTIGUOUS stores.
// Block = 256 thr / 4 waves, owns 256 px. Wave w computes n-tiles 4w..4w+3.
// Per 16-c group: 8 MFMA/wave -> D[n][c] tiles -> LDS transpose buffer
// [16 c][256 n] f32 (double-buffered, XOR-swizzled) -> each output row
// stored as one 64-lane f32x4 = 1 KB contiguous burst.
// ---------------------------------------------------------------------------
__global__ __launch_bounds__(256, 4) void outk(const char* __restrict__ attn,
                                               const char* __restrict__ ws,
                                               float* __restrict__ out) {
    __shared__ char obuf[2][16384];    // [c 16][n 256] f32, row stride 1 KB
    const int b = blockIdx.y;
    const int t = threadIdx.x;
    const int w = t >> 6, l = t & 63, g = l >> 4, ln = l & 15;
    const int n0B = blockIdx.x * 256;

    const char* wpv = ws + WPV_OFF + b * 65536;

    // attn A-frags for this wave's 4 n-tiles (16 B/lane, contiguous rows)
    f16x8 afr[4][2];
    #pragma unroll
    for (int nt = 0; nt < 4; ++nt) {
        const char* ap = attn + ((size_t)b * NPIX + n0B + 64 * w + 16 * nt + ln) * 128 + 16 * g;
        afr[nt][0] = *(const f16x8*)(ap);
        afr[nt][1] = *(const f16x8*)(ap + 64);
    }

    float* ob = out + (size_t)b * CIN * NPIX + n0B + 4 * l;
    const int wr_base = ln * 1024;          // LDS write row = c-local = ln
    const int wr_sw   = (ln & 7) << 4;      // XOR swizzle (write side)
    const int nl0     = 64 * w + 4 * g;     // n-local base (+16*nt, +r)

    #pragma unroll 2
    for (int ct = 0; ct < 32; ++ct) {
        char* buf = obuf[ct & 1];
        f16x8 bfp[2];
        #pragma unroll
        for (int kk = 0; kk < 2; ++kk)
            bfp[kk] = *(const f16x8*)(wpv + (((ct * 2 + kk) * 4 + g) * 16 + ln) * 16);
        #pragma unroll
        for (int nt = 0; nt < 4; ++nt) {
            f32x4 acc = {};
            acc = __builtin_amdgcn_mfma_f32_16x16x32_f16(afr[nt][0], bfp[0], acc, 0, 0, 0);
            acc = __builtin_amdgcn_mfma_f32_16x16x32_f16(afr[nt][1], bfp[1], acc, 0, 0, 0);
            int nl = nl0 + 16 * nt;          // element (n=n0B+nl+r, c=16ct+ln)
            *(f32x4*)(buf + wr_base + ((nl * 4) ^ wr_sw)) = acc;
        }
        __syncthreads();                     // writes visible; prev reads drained
        #pragma unroll
        for (int p = 0; p < 4; ++p) {
            int cl = w + 4 * p;              // row of this store burst
            f32x4 v = *(const f32x4*)(buf + cl * 1024 + ((l * 16) ^ ((cl & 7) << 4)));
            *(f32x4*)(ob + (size_t)(16 * ct + cl) * NPIX) = v;   // 1 KB contiguous/instr
        }
    }
}

// ---------------------------------------------------------------------------
extern "C" void kernel_launch(void* const* d_in, const int* in_sizes, int n_in,
                              void* d_out, int out_size, void* d_ws, size_t ws_size,
                              hipStream_t stream) {
    (void)in_sizes; (void)n_in; (void)out_size; (void)ws_size;
    const float* x   = (const float*)d_in[0];
    const float* ctx = (const float*)d_in[1];
    const float* Wq  = (const float*)d_in[2];
    const float* Wk  = (const float*)d_in[3];
    const float* Wv  = (const float*)d_in[4];
    const float* Wp  = (const float*)d_in[5];
    float* out = (float*)d_out;
    char* ws = (char*)d_ws;

    prep<<<dim3(4, B_), 1024, 0, stream>>>(ctx, Wk, Wv, Wq, Wp, ws);
    simk<<<dim3(NPIX / 128, B_), 256, 0, stream>>>(x, ws, ws + ATTN_OFF);
    outk<<<dim3(NPIX / 256, B_), 256, 0, stream>>>(ws + ATTN_OFF, ws, out);
}

// Round 15
// 149.980 us; speedup vs baseline: 1.2908x; 1.1847x over previous
//
#include <hip/hip_runtime.h>
#include <stdint.h>

// Problem constants
#define B_    8
#define CIN   512
#define NPIX  16384
#define CK    256
#define KCTX  64
#define CV    256

typedef _Float16 f16;
typedef _Float16 f16x4 __attribute__((ext_vector_type(4)));
typedef _Float16 f16x8 __attribute__((ext_vector_type(8)));
typedef float    f32x4 __attribute__((ext_vector_type(4)));

#define LOG2E 1.44269504f

// ws layout (bytes). Tables in exact MFMA fragment order (verified rounds 6-14).
// WQK: A-frag for sim.  byte = ((((s*4+mi)*2+kk)*4+g)*16+ln)*16 + 2*j
//      holds Wqk^T(c,m)*1/16 with c = 64s+32kk+8g+j, m = 16mi+ln
// WPV: B-frag for out.  byte = (((ct*2+kk)*4+g)*16+lnc)*16 + 2*j
//      holds Wpv(c,m) with c = 16ct+lnc, m = 16*(2kk+(j>>2))+4g+(j&3)
#define WQK_OFF  0           // 512 KB : [b][64 KB]
#define WPV_OFF  524288      // 512 KB : [b][64 KB]

#define WAITVM(N) asm volatile("s_waitcnt vmcnt(" #N ")" ::: "memory")
#define LGKM0     asm volatile("s_waitcnt lgkmcnt(0)" ::: "memory")
#define SCHEDB    __builtin_amdgcn_sched_barrier(0)
#define SBAR      __builtin_amdgcn_s_barrier()

__device__ __forceinline__ void gl_lds16(const void* g, void* l) {
    __builtin_amdgcn_global_load_lds(
        (const __attribute__((address_space(1))) uint32_t*)g,
        (__attribute__((address_space(3))) uint32_t*)l, 16, 0, 0);
}

// ---------------------------------------------------------------------------
// prep: grid (16, B), 1024 threads, 64 KB LDS. 4x more parallel than r10:
// path = p>>3 (0=Wqk, 1=Wpv), e = p&7 selects a 64-c chunk. kv GEMM is
// computed redundantly per block (blocks run on otherwise-idle CUs); waves
// w and w&3 produce identical table writes (benign identical-value race).
// ---------------------------------------------------------------------------
__global__ __launch_bounds__(1024) void prep(const float* __restrict__ ctx,
                                             const float* __restrict__ Wk,
                                             const float* __restrict__ Wv,
                                             const float* __restrict__ Wq,
                                             const float* __restrict__ Wp,
                                             char* __restrict__ ws) {
    __shared__ char lds[65536];
    char* ctx_t = lds;              // 32 KB
    char* kv_s  = lds + 32768;      // 32 KB

    const int p = blockIdx.x;
    const int b = blockIdx.y;
    const int path = p >> 3, e = p & 7;
    const int t = threadIdx.x;
    const int w = t >> 6, l = t & 63, g = l >> 4, ln = l & 15;

    // ---- stage ctx transposed: ctx_t[m][c] f16 swz ----
    {
        const int m4 = (t & 15) * 4, c4 = (t >> 4) * 4;
        const float* cp = ctx + (size_t)b * (CV * KCTX) + (size_t)c4 * KCTX + m4;
        f32x4 xr[4];
        #pragma unroll
        for (int i = 0; i < 4; ++i) xr[i] = *(const f32x4*)(cp + (size_t)i * KCTX);
        #pragma unroll
        for (int j = 0; j < 4; ++j) {
            f16x4 v4; v4[0] = (f16)xr[0][j]; v4[1] = (f16)xr[1][j]; v4[2] = (f16)xr[2][j]; v4[3] = (f16)xr[3][j];
            int m = m4 + j;
            *(f16x4*)(ctx_t + m * 512 + 16 * (((c4 >> 3) & 31) ^ (m & 7)) + 2 * (c4 & 7)) = v4;
        }
    }
    __syncthreads();

    // ---- kv GEMM: D[row][m] = (path? Wv : Wk) * ctx, K=256 ----
    {
        const float* W = path ? Wv : Wk;
        const int rbase = 64 * (w >> 2);
        const int mm = 16 * (w & 3) + ln;
        f32x4 acc[4] = {};
        for (int ks = 0; ks < 8; ++ks) {
            f16x8 bf = *(const f16x8*)(ctx_t + mm * 512 + 16 * ((4 * ks + g) ^ (mm & 7)));
            #pragma unroll
            for (int mi = 0; mi < 4; ++mi) {
                int row = rbase + 16 * mi + ln;
                const float* wp0 = W + (size_t)row * CV + 32 * ks + 8 * g;
                f32x4 lo = *(const f32x4*)wp0, hi = *(const f32x4*)(wp0 + 4);
                f16x8 af;
                #pragma unroll
                for (int j = 0; j < 4; ++j) { af[j] = (f16)lo[j]; af[4 + j] = (f16)hi[j]; }
                acc[mi] = __builtin_amdgcn_mfma_f32_16x16x32_f16(af, bf, acc[mi], 0, 0, 0);
            }
        }
        #pragma unroll
        for (int mi = 0; mi < 4; ++mi)
            #pragma unroll
            for (int r = 0; r < 4; ++r) {
                int row = rbase + 16 * mi + 4 * g + r;
                *(f16*)(kv_s + mm * 512 + 16 * ((((row >> 3) & 31)) ^ (mm & 7)) + 2 * (row & 7)) = (f16)acc[mi][r];
            }
    }
    __syncthreads();

    const int cb = 64 * e + 16 * (w & 3);   // this wave's 16-c group in chunk e

    if (path == 0) {
        // ---- Wqk^T[c][m] = sum_kk Wq[kk][c] k[kk][m]; A gathered from global ----
        f32x4 acc2[4] = {};
        const int cA = cb + ln;
        const float* qcol = Wq + cA;
        for (int ks = 0; ks < 8; ++ks) {
            f16x8 af;
            #pragma unroll
            for (int j = 0; j < 8; ++j)
                af[j] = (f16)qcol[(size_t)(32 * ks + 8 * g + j) * CIN];
            #pragma unroll
            for (int ni = 0; ni < 4; ++ni) {
                int m2 = 16 * ni + ln;
                f16x8 bf = *(const f16x8*)(kv_s + m2 * 512 + 16 * ((4 * ks + g) ^ (m2 & 7)));
                acc2[ni] = __builtin_amdgcn_mfma_f32_16x16x32_f16(af, bf, acc2[ni], 0, 0, 0);
            }
        }
        char* dst = ws + WQK_OFF + b * 65536;
        #pragma unroll
        for (int ni = 0; ni < 4; ++ni)
            #pragma unroll
            for (int r = 0; r < 4; ++r) {
                int c = cb + 4 * g + r;                   // k-dim index of sim GEMM
                int s  = c >> 6, kk = (c >> 5) & 1, gk = (c >> 3) & 3, j = c & 7;
                int byte = ((((s * 4 + ni) * 2 + kk) * 4 + gk) * 16 + ln) * 16 + 2 * j;
                *(f16*)(dst + byte) = (f16)(acc2[ni][r] * 0.0625f);   // fold scale 1/16
            }
    } else {
        // ---- Wpv[c][m] = sum_v Wp[c][v] v[v][m]; A direct from global ----
        f32x4 acc2[4] = {};
        const int cA = cb + ln;
        for (int ks = 0; ks < 8; ++ks) {
            const float* pp = Wp + (size_t)cA * CV + 32 * ks + 8 * g;
            f32x4 lo = *(const f32x4*)pp, hi = *(const f32x4*)(pp + 4);
            f16x8 af;
            #pragma unroll
            for (int j = 0; j < 4; ++j) { af[j] = (f16)lo[j]; af[4 + j] = (f16)hi[j]; }
            #pragma unroll
            for (int ni = 0; ni < 4; ++ni) {
                int m2 = 16 * ni + ln;
                f16x8 bf = *(const f16x8*)(kv_s + m2 * 512 + 16 * ((4 * ks + g) ^ (m2 & 7)));
                acc2[ni] = __builtin_amdgcn_mfma_f32_16x16x32_f16(af, bf, acc2[ni], 0, 0, 0);
            }
        }
        char* dst = ws + WPV_OFF + b * 65536;
        #pragma unroll
        for (int ni = 0; ni < 4; ++ni) {
            const int kkm = ni >> 1;
            const int gm  = ln >> 2;
            const int jm  = 4 * (ni & 1) + (ln & 3);
            #pragma unroll
            for (int r = 0; r < 4; ++r) {
                int c = cb + 4 * g + r;                   // output-channel index
                int ct = c >> 4, lnc = c & 15;
                int byte = (((ct * 2 + kkm) * 4 + gm) * 16 + lnc) * 16 + 2 * jm;
                *(f16*)(dst + byte) = (f16)acc2[ni][r];
            }
        }
    }
}

// ---------------------------------------------------------------------------
// fused: r10 skeleton (verified best) + contiguous-store out phase (r14's
// verified mechanism). 1024 threads = 16 waves, 256-px tile, 128 KB dyn LDS.
//  - sim: Wqk table in LDS, x dbuf, depth-4 prefetch, counted vmcnt,
//    ONE barrier per chunk (byte-identical to round 10).
//  - out: Wpv in LDS; D tiles -> 2 x 16 KB LDS transpose buffer (XOR swz)
//    -> each output row stored as one 64-lane f32x4 = 1 KB contiguous burst.
// ---------------------------------------------------------------------------
__global__ __launch_bounds__(1024) void fused(const float* __restrict__ x,
                                              const char* __restrict__ ws,
                                              float* __restrict__ out) {
    extern __shared__ char lds[];              // 128 KB dynamic
    char* tab_l = lds;                         // 64 KB: Wqk, later Wpv
    char* x_s   = lds + 65536;                 // 2 x 32 KB x dbuf; later obuf

    const int b = blockIdx.y;
    const int n0 = blockIdx.x * 256;
    const int t = threadIdx.x;
    const int w = t >> 6, l = t & 63, g = l >> 4, ln = l & 15;
    const int nB = 16 * w + ln;                // wave's MFMA n-row
    const int fnB = (nB ^ (nB >> 3)) & 7;

    const char* wqk_g = ws + WQK_OFF + b * 65536;
    const char* wpv_g = ws + WPV_OFF + b * 65536;
    const float* xb = x + (size_t)b * CIN * NPIX + n0;

    // staging decomposition: thread t -> c-group cg = t>>6 (c = 4cg..4cg+3),
    // n4 = 4*(t&63). 4 f32x4 loads = rows 4cg+i, 1 KB contiguous per instr.
    const int cg = t >> 6;
    const int n4 = 4 * (t & 63);

    f32x4 xr[4][4];   // 4 prefetch slots

#define STAGE_LOAD(S, SLOT)                                                    \
    {                                                                          \
        const float* xp = xb + (size_t)(64 * (S) + 4 * cg) * NPIX + n4;        \
        _Pragma("unroll")                                                      \
        for (int i = 0; i < 4; ++i)                                            \
            xr[SLOT][i] = *(const f32x4*)(xp + (size_t)i * NPIX);              \
    }

#define STAGE_WRITE(BUF, SLOT)                                                 \
    {                                                                          \
        _Pragma("unroll")                                                      \
        for (int j = 0; j < 4; ++j) {                                          \
            f16x4 v4;                                                          \
            v4[0] = (f16)xr[SLOT][0][j]; v4[1] = (f16)xr[SLOT][1][j];          \
            v4[2] = (f16)xr[SLOT][2][j]; v4[3] = (f16)xr[SLOT][3][j];          \
            int nl = n4 + j;                                                   \
            int fn = (nl ^ (nl >> 3)) & 7;                                     \
            *(f16x4*)((BUF) + nl * 128 + 16 * ((cg >> 1) ^ fn) + 8 * (cg & 1)) = v4; \
        }                                                                      \
    }

    // ---- prologue: stage Wqk table (4 ops) + x0..x3 (16 ops) ----
    #pragma unroll
    for (int r = 0; r < 4; ++r) {
        int ch = t + 1024 * r;
        gl_lds16(wqk_g + ch * 16, tab_l + ch * 16);
    }
    SCHEDB;
    STAGE_LOAD(0, 0); SCHEDB;
    STAGE_LOAD(1, 1); SCHEDB;
    STAGE_LOAD(2, 2); SCHEDB;
    STAGE_LOAD(3, 3); SCHEDB;
    WAITVM(12);   // retire wqk-stage + x0; x1..x3 in flight
    SCHEDB;
    STAGE_WRITE(x_s, 0);
    LGKM0; SCHEDB; SBAR; SCHEDB;

    // ---- sim: 8 c-chunks; ONE barrier/iter; only wait = 3-phase-old x ----
    f32x4 accs[4] = {};   // D[m 64][n 16]: acc[mi], m = 16mi + 4g + r
    #pragma unroll
    for (int s = 0; s < 8; ++s) {
        const char* xc = x_s + (s & 1) * 32768;
        #pragma unroll
        for (int kk = 0; kk < 2; ++kk) {
            f16x8 bf = *(const f16x8*)(xc + nB * 128 + 16 * ((4 * kk + g) ^ fnB));
            #pragma unroll
            for (int mi = 0; mi < 4; ++mi) {
                f16x8 af = *(const f16x8*)(tab_l + ((((s * 4 + mi) * 2 + kk) * 4 + g) * 16 + ln) * 16);
                accs[mi] = __builtin_amdgcn_mfma_f32_16x16x32_f16(af, bf, accs[mi], 0, 0, 0);
            }
        }
        SCHEDB;
        if (s < 7) {
            if (s < 4) { STAGE_LOAD(s + 4, (s & 3)); SCHEDB; }
            // retire x(s+1): newer = chunks {s+2..min(s+4,7)}
            if (s < 4)      { WAITVM(12); }
            else if (s == 4){ WAITVM(8); }
            else if (s == 5){ WAITVM(4); }
            else            { WAITVM(0); }
            SCHEDB;
            STAGE_WRITE(x_s + ((s + 1) & 1) * 32768, ((s + 1) & 3));
            LGKM0;
        } else {
            LGKM0;
        }
        SCHEDB; SBAR; SCHEDB;
    }

    // ---- stage Wpv over the table region (all wqk reads behind SBAR) ----
    #pragma unroll
    for (int r = 0; r < 4; ++r) {
        int ch = t + 1024 * r;
        gl_lds16(wpv_g + ch * 16, tab_l + ch * 16);
    }

    // ---- softmax over m (64), in-register (overlaps wpv staging) ----
    float mx = accs[0][0];
    #pragma unroll
    for (int mi = 0; mi < 4; ++mi)
        #pragma unroll
        for (int r = 0; r < 4; ++r) mx = fmaxf(mx, accs[mi][r]);
    mx = fmaxf(mx, __shfl_xor(mx, 16, 64));
    mx = fmaxf(mx, __shfl_xor(mx, 32, 64));
    float pv[4][4];
    float sum = 0.f;
    #pragma unroll
    for (int mi = 0; mi < 4; ++mi)
        #pragma unroll
        for (int r = 0; r < 4; ++r) {
            float pe = __builtin_amdgcn_exp2f((accs[mi][r] - mx) * LOG2E);
            pv[mi][r] = pe; sum += pe;
        }
    sum += __shfl_xor(sum, 16, 64);
    sum += __shfl_xor(sum, 32, 64);
    float inv = 1.f / sum;

    // attn A-frags: (kk,g,j) -> m = 16*(2kk+(j>>2)) + 4g + (j&3)
    f16x8 afr[2];
    #pragma unroll
    for (int kk = 0; kk < 2; ++kk)
        #pragma unroll
        for (int j = 0; j < 8; ++j)
            afr[kk][j] = (f16)(pv[2 * kk + (j >> 2)][j & 3] * inv);

    WAITVM(0); SCHEDB; SBAR; SCHEDB;   // Wpv staged; all x_s reads done

    // ---- out: LDS-transposed contiguous stores (r14 mechanism) ----
    // writer: D elem (c-local=ln, n-local=16w+4g+r) -> obuf[ln][nl] XOR-swz
    // reader: wave w reads row w (256 n = 1 KB) -> out row 16ct+w, 1 KB burst
    const int wrbyte = ln * 1024 + (((16 * w + 4 * g) * 4) ^ ((ln & 7) << 4));
    const int rdbyte = w * 1024 + ((l * 16) ^ ((w & 7) << 4));
    float* obase = out + (size_t)b * CIN * NPIX + n0 + 4 * l;

    {   // ct = 0: compute + write
        f32x4 acc = {};
        #pragma unroll
        for (int kk = 0; kk < 2; ++kk) {
            f16x8 bfp = *(const f16x8*)(tab_l + ((kk * 4 + g) * 16 + ln) * 16);
            acc = __builtin_amdgcn_mfma_f32_16x16x32_f16(afr[kk], bfp, acc, 0, 0, 0);
        }
        *(f32x4*)(x_s + wrbyte) = acc;
    }
    __syncthreads();
    #pragma unroll 2
    for (int ct = 0; ct < 32; ++ct) {
        // read + store ct (1 KB contiguous per wave-instruction)
        f32x4 v = *(const f32x4*)(x_s + (ct & 1) * 16384 + rdbyte);
        *(f32x4*)(obase + (size_t)(16 * ct + w) * NPIX) = v;
        // compute + write ct+1 into the other buffer
        if (ct < 31) {
            f32x4 acc = {};
            #pragma unroll
            for (int kk = 0; kk < 2; ++kk) {
                f16x8 bfp = *(const f16x8*)(tab_l + ((((ct + 1) * 2 + kk) * 4 + g) * 16 + ln) * 16);
                acc = __builtin_amdgcn_mfma_f32_16x16x32_f16(afr[kk], bfp, acc, 0, 0, 0);
            }
            *(f32x4*)(x_s + ((ct + 1) & 1) * 16384 + wrbyte) = acc;
        }
        __syncthreads();
    }
}

// ---------------------------------------------------------------------------
extern "C" void kernel_launch(void* const* d_in, const int* in_sizes, int n_in,
                              void* d_out, int out_size, void* d_ws, size_t ws_size,
                              hipStream_t stream) {
    (void)in_sizes; (void)n_in; (void)out_size; (void)ws_size;
    const float* x   = (const float*)d_in[0];
    const float* ctx = (const float*)d_in[1];
    const float* Wq  = (const float*)d_in[2];
    const float* Wk  = (const float*)d_in[3];
    const float* Wv  = (const float*)d_in[4];
    const float* Wp  = (const float*)d_in[5];
    float* out = (float*)d_out;
    char* ws = (char*)d_ws;

    prep<<<dim3(16, B_), 1024, 0, stream>>>(ctx, Wk, Wv, Wq, Wp, ws);
    fused<<<dim3(NPIX / 256, B_), 1024, 131072, stream>>>(x, ws, out);
}